// Round 8
// baseline (102.769 us; speedup 1.0000x reference)
//
#include <hip/hip_runtime.h>

#define NN 50000
#define NPAD 50048   // 782*64
#define NE 320000
#define D 256
#define CAP 64       // per-node in-edge capacity; deg ~ Poisson(6.4)
#define NCSR 1250    // csr-fill blocks
#define NCONV 6250   // convert blocks: NN*D/(256*8)

typedef __bf16 bf16x8 __attribute__((ext_vector_type(8)));
typedef float f32x4 __attribute__((ext_vector_type(4)));

__device__ __forceinline__ unsigned short f2bf(float f) {
    unsigned u = __builtin_bit_cast(unsigned, f);
    unsigned r = u + 0x7FFFu + ((u >> 16) & 1u);   // RNE
    return (unsigned short)(r >> 16);
}
__device__ __forceinline__ float bflo(unsigned u) {
    return __builtin_bit_cast(float, u << 16);
}
__device__ __forceinline__ float bfhi(unsigned u) {
    return __builtin_bit_cast(float, u & 0xFFFF0000u);
}
__device__ __forceinline__ unsigned packbf(float lo, float hi) {
    return (unsigned)f2bf(lo) | ((unsigned)f2bf(hi) << 16);
}

// k1: WTT[j][k] bf16 (stride 512): k<256 -> w1[j][k]; k>=256 -> (w2@w3)[j][k-256]
//     bvec[j] = (w2@b3)[j]; also zeroes cnt (65536 threads >= NN)
__global__ __launch_bounds__(256) void prep_weights(
        const float* __restrict__ w1, const float* __restrict__ w2,
        const float* __restrict__ w3, const float* __restrict__ b3,
        unsigned short* __restrict__ WTT, float* __restrict__ bvec,
        int* __restrict__ cnt) {
    const int j = blockIdx.x;
    const int k = threadIdx.x;
    const int g = j * 256 + k;
    if (g < NN) cnt[g] = 0;
    __shared__ float w2row[D];
    __shared__ float red[D];
    w2row[k] = w2[j * D + k];
    __syncthreads();
    float acc = 0.f;
    #pragma unroll 8
    for (int o = 0; o < D; ++o) acc += w2row[o] * w3[o * D + k];
    WTT[(size_t)j * 512 + k]     = f2bf(w1[j * D + k]);
    WTT[(size_t)j * 512 + D + k] = f2bf(acc);
    red[k] = w2row[k] * b3[k];
    __syncthreads();
    for (int s = 128; s > 0; s >>= 1) {
        if (k < s) red[k] += red[k + s];
        __syncthreads();
    }
    if (k == 0) bvec[j] = red[0];
}

// k2: blocks [0,NCSR) fill csr (dispatch first so atomics overlap convert);
//     blocks [NCSR, NCSR+NCONV) convert x->bf16.
__global__ __launch_bounds__(256) void convert_and_csr(
        const float* __restrict__ x, unsigned short* __restrict__ xbf,
        const int* __restrict__ ei, int* __restrict__ csr, int* __restrict__ cnt) {
    const int b = blockIdx.x;
    if (b < NCSR) {
        const int e = b * 256 + threadIdx.x;
        if (e < NE) {
            const int src = ei[e];
            const int dst = ei[NE + e];
            const int pos = atomicAdd(cnt + dst, 1);
            if (pos < CAP) csr[(size_t)dst * CAP + pos] = src;
        }
    } else {
        const size_t i = ((size_t)(b - NCSR) * 256 + threadIdx.x) * 8;
        const float4 a0 = *reinterpret_cast<const float4*>(x + i);
        const float4 a1 = *reinterpret_cast<const float4*>(x + i + 4);
        ushort4 o0 = {f2bf(a0.x), f2bf(a0.y), f2bf(a0.z), f2bf(a0.w)};
        ushort4 o1 = {f2bf(a1.x), f2bf(a1.y), f2bf(a1.z), f2bf(a1.w)};
        *reinterpret_cast<ushort4*>(xbf + i)     = o0;
        *reinterpret_cast<ushort4*>(xbf + i + 4) = o1;
    }
}

// k3: half-wave per node; CSR indices preloaded coalesced + shfl-broadcast;
// 4-deep row-gather unroll. (LLC-gather-BW bound; leave as-is.)
__global__ __launch_bounds__(256) void agg_gather(
        const unsigned short* __restrict__ xbf, const int* __restrict__ csr,
        const int* __restrict__ cnt, unsigned short* __restrict__ aggbf) {
    const int node = blockIdx.x * 8 + (threadIdx.x >> 5);
    const int l32  = threadIdx.x & 31;
    if (node >= NN) return;
    int d = cnt[node]; if (d > CAP) d = CAP;
    const int* __restrict__ row = csr + (size_t)node * CAP;
    const int d32 = d < 32 ? d : 32;
    int myidx = 0;
    if (l32 < d32) myidx = row[l32];
    float a0 = 0.f, a1 = 0.f, a2 = 0.f, a3 = 0.f;
    float a4 = 0.f, a5 = 0.f, a6 = 0.f, a7 = 0.f;
    int i = 0;
    for (; i + 4 <= d32; i += 4) {
        const int s0 = __shfl(myidx, i,     32);
        const int s1 = __shfl(myidx, i + 1, 32);
        const int s2 = __shfl(myidx, i + 2, 32);
        const int s3 = __shfl(myidx, i + 3, 32);
        const uint4 p = *reinterpret_cast<const uint4*>(xbf + (size_t)s0 * D + l32 * 8);
        const uint4 q = *reinterpret_cast<const uint4*>(xbf + (size_t)s1 * D + l32 * 8);
        const uint4 u = *reinterpret_cast<const uint4*>(xbf + (size_t)s2 * D + l32 * 8);
        const uint4 v = *reinterpret_cast<const uint4*>(xbf + (size_t)s3 * D + l32 * 8);
        a0 += (bflo(p.x) + bflo(q.x)) + (bflo(u.x) + bflo(v.x));
        a1 += (bfhi(p.x) + bfhi(q.x)) + (bfhi(u.x) + bfhi(v.x));
        a2 += (bflo(p.y) + bflo(q.y)) + (bflo(u.y) + bflo(v.y));
        a3 += (bfhi(p.y) + bfhi(q.y)) + (bfhi(u.y) + bfhi(v.y));
        a4 += (bflo(p.z) + bflo(q.z)) + (bflo(u.z) + bflo(v.z));
        a5 += (bfhi(p.z) + bfhi(q.z)) + (bfhi(u.z) + bfhi(v.z));
        a6 += (bflo(p.w) + bflo(q.w)) + (bflo(u.w) + bflo(v.w));
        a7 += (bfhi(p.w) + bfhi(q.w)) + (bfhi(u.w) + bfhi(v.w));
    }
    for (; i < d32; ++i) {
        const int s = __shfl(myidx, i, 32);
        const uint4 p = *reinterpret_cast<const uint4*>(xbf + (size_t)s * D + l32 * 8);
        a0 += bflo(p.x); a1 += bfhi(p.x);
        a2 += bflo(p.y); a3 += bfhi(p.y);
        a4 += bflo(p.z); a5 += bfhi(p.z);
        a6 += bflo(p.w); a7 += bfhi(p.w);
    }
    for (; i < d; ++i) {
        const uint4 p = *reinterpret_cast<const uint4*>(xbf + (size_t)row[i] * D + l32 * 8);
        a0 += bflo(p.x); a1 += bfhi(p.x);
        a2 += bflo(p.y); a3 += bfhi(p.y);
        a4 += bflo(p.z); a5 += bfhi(p.z);
        a6 += bflo(p.w); a7 += bfhi(p.w);
    }
    uint4 o = {packbf(a0, a1), packbf(a2, a3), packbf(a4, a5), packbf(a6, a7)};
    *reinterpret_cast<uint4*>(aggbf + (size_t)node * D + l32 * 8) = o;
}

// k4: out[64 x 128 tile] = [xbf | aggbf] @ WTT^T + deg*bvec
// Double-buffered LDS (2 x 24KB), counted-vmcnt raw-barrier pipeline:
// wait vmcnt(6) keeps the NEXT tile's 6 global_load_lds in flight across
// the barrier (no full drain). stage(kt+2) issued after the post-compute
// barrier into the freed buffer. 3 blocks/CU overlap on top.
__global__ __launch_bounds__(256) void gemm_tiled(
        const unsigned short* __restrict__ xbf, const unsigned short* __restrict__ aggbf,
        const unsigned short* __restrict__ WTT, const float* __restrict__ bvec,
        const int* __restrict__ cnt, float* __restrict__ out) {
    __shared__ __align__(16) unsigned short ldsA[2][64 * 64];    // 2 x 8 KB
    __shared__ __align__(16) unsigned short ldsB[2][128 * 64];   // 2 x 16 KB

    const int tid  = threadIdx.x;
    const int w    = tid >> 6;
    const int lane = tid & 63;
    const int l16  = lane & 15;
    const int g4   = lane >> 4;          // 0..3
    const int wm   = w >> 1, wn = w & 1;
    const int gr0  = (blockIdx.x >> 1) * 64;
    const int nb0  = (blockIdx.x & 1) * 128;

    auto stage = [&](int kt, int b) {
        const unsigned short* __restrict__ srcA = (kt < 4) ? xbf : aggbf;
        const int kcA = (kt & 3) * 64;
        #pragma unroll
        for (int p = 0; p < 2; ++p) {
            const int idx = p * 256 + w * 64 + lane;      // 16B unit id
            const int r = idx >> 3, c = idx & 7;
            const int sw = (c ^ (r & 7)) << 3;
            const unsigned short* gp = srcA + ((size_t)(gr0 + r) << 8) + kcA + sw;
            unsigned short* lp = &ldsA[b][(p * 256 + w * 64) << 3];
            __builtin_amdgcn_global_load_lds(
                (const __attribute__((address_space(1))) void*)(const void*)gp,
                (__attribute__((address_space(3))) void*)(void*)lp, 16, 0, 0);
        }
        const int kcB = kt * 64;
        #pragma unroll
        for (int p = 0; p < 4; ++p) {
            const int idx = p * 256 + w * 64 + lane;
            const int r = idx >> 3, c = idx & 7;
            const int sw = (c ^ (r & 7)) << 3;
            const unsigned short* gp = WTT + ((size_t)(nb0 + r) << 9) + kcB + sw;
            unsigned short* lp = &ldsB[b][(p * 256 + w * 64) << 3];
            __builtin_amdgcn_global_load_lds(
                (const __attribute__((address_space(1))) void*)(const void*)gp,
                (__attribute__((address_space(3))) void*)(void*)lp, 16, 0, 0);
        }
    };

    f32x4 acc[2][4];
    #pragma unroll
    for (int a = 0; a < 2; ++a)
        #pragma unroll
        for (int b = 0; b < 4; ++b) acc[a][b] = (f32x4)0.f;

    stage(0, 0);
    stage(1, 1);
    #pragma unroll
    for (int kt = 0; kt < 8; ++kt) {
        const int cur = kt & 1;
        if (kt < 7) asm volatile("s_waitcnt vmcnt(6)" ::: "memory");
        else        asm volatile("s_waitcnt vmcnt(0)" ::: "memory");
        __builtin_amdgcn_s_barrier();      // all waves' tile-kt loads landed

        #pragma unroll
        for (int kh = 0; kh < 2; ++kh) {
            const int cb = kh * 4 + g4;                       // unit 0..7
            bf16x8 af[2], bfr[4];
            #pragma unroll
            for (int f = 0; f < 2; ++f) {
                const int ra = wm * 32 + f * 16 + l16;
                af[f] = *reinterpret_cast<const bf16x8*>(
                    &ldsA[cur][(ra * 8 + (cb ^ (ra & 7))) * 8]);
            }
            #pragma unroll
            for (int f = 0; f < 4; ++f) {
                const int rb = wn * 64 + f * 16 + l16;
                bfr[f] = *reinterpret_cast<const bf16x8*>(
                    &ldsB[cur][(rb * 8 + (cb ^ (rb & 7))) * 8]);
            }
            #pragma unroll
            for (int fm = 0; fm < 2; ++fm)
                #pragma unroll
                for (int fn = 0; fn < 4; ++fn)
                    acc[fm][fn] = __builtin_amdgcn_mfma_f32_16x16x32_bf16(
                        af[fm], bfr[fn], acc[fm][fn], 0, 0, 0);
        }
        __builtin_amdgcn_s_barrier();      // everyone done reading buf[cur]
        if (kt < 6) stage(kt + 2, cur);    // refill freed buffer
    }

    // epilogue: out = acc + deg*bvec ; C/D layout col=lane&15, row=(lane>>4)*4+i
    const int col0 = nb0 + wn * 64 + l16;
    float bv[4];
    #pragma unroll
    for (int fn = 0; fn < 4; ++fn) bv[fn] = bvec[col0 + fn * 16];
    #pragma unroll
    for (int fm = 0; fm < 2; ++fm) {
        #pragma unroll
        for (int i = 0; i < 4; ++i) {
            const int row = gr0 + wm * 32 + fm * 16 + g4 * 4 + i;
            if (row < NN) {
                const float dg = (float)cnt[row];
                float* op = out + ((size_t)row << 8) + col0;
                #pragma unroll
                for (int fn = 0; fn < 4; ++fn)
                    op[fn * 16] = acc[fm][fn][i] + dg * bv[fn];
            }
        }
    }
}

extern "C" void kernel_launch(void* const* d_in, const int* in_sizes, int n_in,
                              void* d_out, int out_size, void* d_ws, size_t ws_size,
                              hipStream_t stream) {
    const float* x  = (const float*)d_in[0];
    const int*   ei = (const int*)d_in[1];
    const float* w1 = (const float*)d_in[2];
    const float* w2 = (const float*)d_in[3];
    const float* w3 = (const float*)d_in[4];
    const float* b3 = (const float*)d_in[5];
    float* out = (float*)d_out;

    unsigned short* xbf   = (unsigned short*)d_ws;               // NPAD*256
    unsigned short* aggbf = xbf + (size_t)NPAD * D;              // NPAD*256
    unsigned short* WTT   = aggbf + (size_t)NPAD * D;            // 256*512
    float* bvec = (float*)(WTT + (size_t)D * 512);               // 256
    int*   cnt  = (int*)(bvec + D);                              // NN
    int*   csr  = cnt + NN;                                      // NN*CAP

    prep_weights<<<D, 256, 0, stream>>>(w1, w2, w3, b3, WTT, bvec, cnt);
    convert_and_csr<<<NCSR + NCONV, 256, 0, stream>>>(x, xbf, ei, csr, cnt);
    agg_gather<<<(NN + 7) / 8, 256, 0, stream>>>(xbf, csr, cnt, aggbf);
    gemm_tiled<<<(NPAD / 64) * 2, 256, 0, stream>>>(xbf, aggbf, WTT, bvec, cnt, out);
}

// Round 9
// 96.148 us; speedup vs baseline: 1.0689x; 1.0689x over previous
//
#include <hip/hip_runtime.h>

#define NN 50000
#define NPAD 50048   // 782*64
#define NE 320000
#define D 256
#define CAP 64       // per-node in-edge capacity; deg ~ Poisson(6.4)
#define NPREP 256    // prep blocks in merged k1
#define NCONV 6250   // convert blocks: NN*D/(256*8)

typedef __bf16 bf16x8 __attribute__((ext_vector_type(8)));
typedef float f32x4 __attribute__((ext_vector_type(4)));

__device__ __forceinline__ unsigned short f2bf(float f) {
    unsigned u = __builtin_bit_cast(unsigned, f);
    unsigned r = u + 0x7FFFu + ((u >> 16) & 1u);   // RNE
    return (unsigned short)(r >> 16);
}
__device__ __forceinline__ float bflo(unsigned u) {
    return __builtin_bit_cast(float, u << 16);
}
__device__ __forceinline__ float bfhi(unsigned u) {
    return __builtin_bit_cast(float, u & 0xFFFF0000u);
}
__device__ __forceinline__ unsigned packbf(float lo, float hi) {
    return (unsigned)f2bf(lo) | ((unsigned)f2bf(hi) << 16);
}

// k1 (merged): blocks [0,NPREP): weight prep + cnt zeroing;
//              blocks [NPREP, NPREP+NCONV): x -> bf16 convert.
// WTT[j][k] bf16 (stride 512): k<256 -> w1[j][k]; k>=256 -> (w2@w3)[j][k-256]
// bvec[j] = (w2@b3)[j]
__global__ __launch_bounds__(256) void prep_and_convert(
        const float* __restrict__ w1, const float* __restrict__ w2,
        const float* __restrict__ w3, const float* __restrict__ b3,
        const float* __restrict__ x, unsigned short* __restrict__ xbf,
        unsigned short* __restrict__ WTT, float* __restrict__ bvec,
        int* __restrict__ cnt) {
    const int b = blockIdx.x;
    const int k = threadIdx.x;
    if (b < NPREP) {
        const int j = b;
        const int g = j * 256 + k;
        if (g < NN) cnt[g] = 0;
        __shared__ float w2row[D];
        __shared__ float red[D];
        w2row[k] = w2[j * D + k];
        __syncthreads();
        float acc = 0.f;
        #pragma unroll 8
        for (int o = 0; o < D; ++o) acc += w2row[o] * w3[o * D + k];
        WTT[(size_t)j * 512 + k]     = f2bf(w1[j * D + k]);
        WTT[(size_t)j * 512 + D + k] = f2bf(acc);
        red[k] = w2row[k] * b3[k];
        __syncthreads();
        for (int s = 128; s > 0; s >>= 1) {
            if (k < s) red[k] += red[k + s];
            __syncthreads();
        }
        if (k == 0) bvec[j] = red[0];
    } else {
        const size_t i = ((size_t)(b - NPREP) * 256 + k) * 8;
        const float4 a0 = *reinterpret_cast<const float4*>(x + i);
        const float4 a1 = *reinterpret_cast<const float4*>(x + i + 4);
        ushort4 o0 = {f2bf(a0.x), f2bf(a0.y), f2bf(a0.z), f2bf(a0.w)};
        ushort4 o1 = {f2bf(a1.x), f2bf(a1.y), f2bf(a1.z), f2bf(a1.w)};
        *reinterpret_cast<ushort4*>(xbf + i)     = o0;
        *reinterpret_cast<ushort4*>(xbf + i + 4) = o1;
    }
}

// k2: csr fill (needs cnt zeroed by k1)
__global__ __launch_bounds__(256) void fill_csr(
        const int* __restrict__ ei, int* __restrict__ csr, int* __restrict__ cnt) {
    const int e = blockIdx.x * 256 + threadIdx.x;
    if (e >= NE) return;
    const int src = ei[e];
    const int dst = ei[NE + e];
    const int pos = atomicAdd(cnt + dst, 1);
    if (pos < CAP) csr[(size_t)dst * CAP + pos] = src;
}

// k3: half-wave per node; CSR indices preloaded coalesced + shfl-broadcast;
// 4-deep row-gather unroll. (control: unchanged from R6)
__global__ __launch_bounds__(256) void agg_gather(
        const unsigned short* __restrict__ xbf, const int* __restrict__ csr,
        const int* __restrict__ cnt, unsigned short* __restrict__ aggbf) {
    const int node = blockIdx.x * 8 + (threadIdx.x >> 5);
    const int l32  = threadIdx.x & 31;
    if (node >= NN) return;
    int d = cnt[node]; if (d > CAP) d = CAP;
    const int* __restrict__ row = csr + (size_t)node * CAP;
    const int d32 = d < 32 ? d : 32;
    int myidx = 0;
    if (l32 < d32) myidx = row[l32];
    float a0 = 0.f, a1 = 0.f, a2 = 0.f, a3 = 0.f;
    float a4 = 0.f, a5 = 0.f, a6 = 0.f, a7 = 0.f;
    int i = 0;
    for (; i + 4 <= d32; i += 4) {
        const int s0 = __shfl(myidx, i,     32);
        const int s1 = __shfl(myidx, i + 1, 32);
        const int s2 = __shfl(myidx, i + 2, 32);
        const int s3 = __shfl(myidx, i + 3, 32);
        const uint4 p = *reinterpret_cast<const uint4*>(xbf + (size_t)s0 * D + l32 * 8);
        const uint4 q = *reinterpret_cast<const uint4*>(xbf + (size_t)s1 * D + l32 * 8);
        const uint4 u = *reinterpret_cast<const uint4*>(xbf + (size_t)s2 * D + l32 * 8);
        const uint4 v = *reinterpret_cast<const uint4*>(xbf + (size_t)s3 * D + l32 * 8);
        a0 += (bflo(p.x) + bflo(q.x)) + (bflo(u.x) + bflo(v.x));
        a1 += (bfhi(p.x) + bfhi(q.x)) + (bfhi(u.x) + bfhi(v.x));
        a2 += (bflo(p.y) + bflo(q.y)) + (bflo(u.y) + bflo(v.y));
        a3 += (bfhi(p.y) + bfhi(q.y)) + (bfhi(u.y) + bfhi(v.y));
        a4 += (bflo(p.z) + bflo(q.z)) + (bflo(u.z) + bflo(v.z));
        a5 += (bfhi(p.z) + bfhi(q.z)) + (bfhi(u.z) + bfhi(v.z));
        a6 += (bflo(p.w) + bflo(q.w)) + (bflo(u.w) + bflo(v.w));
        a7 += (bfhi(p.w) + bfhi(q.w)) + (bfhi(u.w) + bfhi(v.w));
    }
    for (; i < d32; ++i) {
        const int s = __shfl(myidx, i, 32);
        const uint4 p = *reinterpret_cast<const uint4*>(xbf + (size_t)s * D + l32 * 8);
        a0 += bflo(p.x); a1 += bfhi(p.x);
        a2 += bflo(p.y); a3 += bfhi(p.y);
        a4 += bflo(p.z); a5 += bfhi(p.z);
        a6 += bflo(p.w); a7 += bfhi(p.w);
    }
    for (; i < d; ++i) {
        const uint4 p = *reinterpret_cast<const uint4*>(xbf + (size_t)row[i] * D + l32 * 8);
        a0 += bflo(p.x); a1 += bfhi(p.x);
        a2 += bflo(p.y); a3 += bfhi(p.y);
        a4 += bflo(p.z); a5 += bfhi(p.z);
        a6 += bflo(p.w); a7 += bfhi(p.w);
    }
    uint4 o = {packbf(a0, a1), packbf(a2, a3), packbf(a4, a5), packbf(a6, a7)};
    *reinterpret_cast<uint4*>(aggbf + (size_t)node * D + l32 * 8) = o;
}

// k4: out[64 x 128 tile] = [xbf | aggbf] @ WTT^T + deg*bvec
// Double-buffered LDS, counted-vmcnt pipeline (R7) + bijective chunked XCD
// swizzle (m204): work-ids 2k,2k+1 (the two col-blocks sharing one A-stripe)
// land at consecutive positions in the SAME XCD chunk -> second A read is an
// XCD-L2 hit, halving LLC A-traffic.
__global__ __launch_bounds__(256) void gemm_tiled(
        const unsigned short* __restrict__ xbf, const unsigned short* __restrict__ aggbf,
        const unsigned short* __restrict__ WTT, const float* __restrict__ bvec,
        const int* __restrict__ cnt, float* __restrict__ out) {
    __shared__ __align__(16) unsigned short ldsA[2][64 * 64];    // 2 x 8 KB
    __shared__ __align__(16) unsigned short ldsB[2][128 * 64];   // 2 x 16 KB

    // bijective chunked XCD swizzle: nwg = 1564, q=195, r=4
    const int nwg = gridDim.x;
    const int q   = nwg >> 3, r = nwg & 7;
    const int xcd = blockIdx.x & 7, pos = blockIdx.x >> 3;
    const int wg  = (xcd < r ? xcd * (q + 1) : r * (q + 1) + (xcd - r) * q) + pos;

    const int tid  = threadIdx.x;
    const int w    = tid >> 6;
    const int lane = tid & 63;
    const int l16  = lane & 15;
    const int g4   = lane >> 4;          // 0..3
    const int wm   = w >> 1, wn = w & 1;
    const int gr0  = (wg >> 1) * 64;
    const int nb0  = (wg & 1) * 128;

    auto stage = [&](int kt, int b) {
        const unsigned short* __restrict__ srcA = (kt < 4) ? xbf : aggbf;
        const int kcA = (kt & 3) * 64;
        #pragma unroll
        for (int p = 0; p < 2; ++p) {
            const int idx = p * 256 + w * 64 + lane;      // 16B unit id
            const int rr = idx >> 3, c = idx & 7;
            const int sw = (c ^ (rr & 7)) << 3;
            const unsigned short* gp = srcA + ((size_t)(gr0 + rr) << 8) + kcA + sw;
            unsigned short* lp = &ldsA[b][(p * 256 + w * 64) << 3];
            __builtin_amdgcn_global_load_lds(
                (const __attribute__((address_space(1))) void*)(const void*)gp,
                (__attribute__((address_space(3))) void*)(void*)lp, 16, 0, 0);
        }
        const int kcB = kt * 64;
        #pragma unroll
        for (int p = 0; p < 4; ++p) {
            const int idx = p * 256 + w * 64 + lane;
            const int rr = idx >> 3, c = idx & 7;
            const int sw = (c ^ (rr & 7)) << 3;
            const unsigned short* gp = WTT + ((size_t)(nb0 + rr) << 9) + kcB + sw;
            unsigned short* lp = &ldsB[b][(p * 256 + w * 64) << 3];
            __builtin_amdgcn_global_load_lds(
                (const __attribute__((address_space(1))) void*)(const void*)gp,
                (__attribute__((address_space(3))) void*)(void*)lp, 16, 0, 0);
        }
    };

    f32x4 acc[2][4];
    #pragma unroll
    for (int a = 0; a < 2; ++a)
        #pragma unroll
        for (int b = 0; b < 4; ++b) acc[a][b] = (f32x4)0.f;

    stage(0, 0);
    stage(1, 1);
    #pragma unroll
    for (int kt = 0; kt < 8; ++kt) {
        const int cur = kt & 1;
        if (kt < 7) asm volatile("s_waitcnt vmcnt(6)" ::: "memory");
        else        asm volatile("s_waitcnt vmcnt(0)" ::: "memory");
        __builtin_amdgcn_s_barrier();      // all waves' tile-kt loads landed

        #pragma unroll
        for (int kh = 0; kh < 2; ++kh) {
            const int cb = kh * 4 + g4;                       // unit 0..7
            bf16x8 af[2], bfr[4];
            #pragma unroll
            for (int f = 0; f < 2; ++f) {
                const int ra = wm * 32 + f * 16 + l16;
                af[f] = *reinterpret_cast<const bf16x8*>(
                    &ldsA[cur][(ra * 8 + (cb ^ (ra & 7))) * 8]);
            }
            #pragma unroll
            for (int f = 0; f < 4; ++f) {
                const int rb = wn * 64 + f * 16 + l16;
                bfr[f] = *reinterpret_cast<const bf16x8*>(
                    &ldsB[cur][(rb * 8 + (cb ^ (rb & 7))) * 8]);
            }
            #pragma unroll
            for (int fm = 0; fm < 2; ++fm)
                #pragma unroll
                for (int fn = 0; fn < 4; ++fn)
                    acc[fm][fn] = __builtin_amdgcn_mfma_f32_16x16x32_bf16(
                        af[fm], bfr[fn], acc[fm][fn], 0, 0, 0);
        }
        __builtin_amdgcn_s_barrier();      // everyone done reading buf[cur]
        if (kt < 6) stage(kt + 2, cur);    // refill freed buffer
    }

    // epilogue: out = acc + deg*bvec ; C/D layout col=lane&15, row=(lane>>4)*4+i
    const int col0 = nb0 + wn * 64 + l16;
    float bv[4];
    #pragma unroll
    for (int fn = 0; fn < 4; ++fn) bv[fn] = bvec[col0 + fn * 16];
    #pragma unroll
    for (int fm = 0; fm < 2; ++fm) {
        #pragma unroll
        for (int i = 0; i < 4; ++i) {
            const int row = gr0 + wm * 32 + fm * 16 + g4 * 4 + i;
            if (row < NN) {
                const float dg = (float)cnt[row];
                float* op = out + ((size_t)row << 8) + col0;
                #pragma unroll
                for (int fn = 0; fn < 4; ++fn)
                    op[fn * 16] = acc[fm][fn][i] + dg * bv[fn];
            }
        }
    }
}

extern "C" void kernel_launch(void* const* d_in, const int* in_sizes, int n_in,
                              void* d_out, int out_size, void* d_ws, size_t ws_size,
                              hipStream_t stream) {
    const float* x  = (const float*)d_in[0];
    const int*   ei = (const int*)d_in[1];
    const float* w1 = (const float*)d_in[2];
    const float* w2 = (const float*)d_in[3];
    const float* w3 = (const float*)d_in[4];
    const float* b3 = (const float*)d_in[5];
    float* out = (float*)d_out;

    unsigned short* xbf   = (unsigned short*)d_ws;               // NPAD*256
    unsigned short* aggbf = xbf + (size_t)NPAD * D;              // NPAD*256
    unsigned short* WTT   = aggbf + (size_t)NPAD * D;            // 256*512
    float* bvec = (float*)(WTT + (size_t)D * 512);               // 256
    int*   cnt  = (int*)(bvec + D);                              // NN
    int*   csr  = cnt + NN;                                      // NN*CAP

    prep_and_convert<<<NPREP + NCONV, 256, 0, stream>>>(
        w1, w2, w3, b3, x, xbf, WTT, bvec, cnt);
    fill_csr<<<(NE + 255) / 256, 256, 0, stream>>>(ei, csr, cnt);
    agg_gather<<<(NN + 7) / 8, 256, 0, stream>>>(xbf, csr, cnt, aggbf);
    gemm_tiled<<<(NPAD / 64) * 2, 256, 0, stream>>>(xbf, aggbf, WTT, bvec, cnt, out);
}